// Round 11
// baseline (139.422 us; speedup 1.0000x reference)
//
#include <hip/hip_runtime.h>
#include <math.h>

// AutoregressiveFlowLayer MI355X — round 20.
// R19 post-mortem: no spill but occupancy pinned at 50% (2 blocks/CU) across
// EVERY non-spilling config (R12/13/16/19) -> 16 waves/CU is the hard operating
// point; occupancy axis closed. At 47us all pipes <=26%; MFMA floor ~7us, HBM
// floor ~7us -> the cost is barrier-lockstep latency (2 barriers x 11 tiles x
// ds_read->MFMA-chain->pack->store->drain at 4 waves/SIMD). Every lockstep
// variant (R13 merge, R18 specialization, R16/R19 grid surgery) landed 47-53.
// R20 = BARRIERLESS wave-independent pipeline:
//  - each wave computes the FULL P1->P2->P3+epilogue for its own 16 batch rows;
//    iterations (4 per wave) fully independent; NO barriers after weight staging.
//  - weights in block-shared read-only LDS (W1 10.2K + W2 34.8K + Wout 17.4K);
//  - h1/h2 C-layout -> B-layout transpose via per-wave PRIVATE 1.25KB LDS
//    buffer in 32-k pairs (write pair -> read B-frag -> MFMAs), ordered by the
//    wave's own lgkmcnt — no inter-wave coupling. Mapping: c1 = 16mt+4q'+i =
//    32ksp + kloc, kloc = 16(mt&1)+4q'+i; read at kloc=8q = B-frag k=32ksp+8q..+7.
//  - gather directly yields P1's B-frag (lane(q,b) loads feats 8q..8q+7 of row
//    b): xg staging deleted. Epilogue x re-loaded f32 (L2-hot, better accuracy).
//  - LDS 71KB -> 2 blocks/CU; grid 512 = exactly 2/CU; same-row blocks share an
//    XCD (bid%8=blk%8). __launch_bounds__(512,4): 128-reg cap >= ~105 peak.
// Predict: 47 -> 28-36us; MfmaUtil 18-25; WRITE ~1-2MB + VGPR ~100-128 = no
// spill. If >=47us: wave-independence wasn't the lever -> structure ceiling.

#define RR 32
#define DD 1024
#define HH 128
#define OO 64

#define SW1 40    // u16 k-stride, W1^T [col][k], k=32 (+8 pad; 16B-aligned rows)
#define SSC 136   // u16 k-stride, W2^T/Wout^T [col][k], k=128
#define SST 40    // u16 k-stride, per-wave staging [b][kloc], kloc=32 (+8 pad)

typedef _Float16 f16x8_t __attribute__((ext_vector_type(8)));
typedef float f32x4_t __attribute__((ext_vector_type(4)));
typedef unsigned short u16;
typedef unsigned int u32;

__device__ __forceinline__ u16 f16b(float x) {
    _Float16 h = (_Float16)x;            // v_cvt_f16_f32, RNE
    union { _Float16 f; u16 u; } c; c.f = h; return c.u;
}
__device__ __forceinline__ f32x4_t mfma16h(f16x8_t a, f16x8_t b, f32x4_t c) {
    return __builtin_amdgcn_mfma_f32_16x16x32_f16(a, b, c, 0, 0, 0);
}

// stage [K x 32] weight slice (row-major [k][col], ld ldc, col offset c0) into
// fp16 [col][k] LDS (k-stride sd), conflict-free 4x4 transpose. tid in [0,256).
__device__ __forceinline__ void stage_block16(const float* __restrict__ W,
                                              const int* __restrict__ M,
                                              int ldc, int c0, int K,
                                              u16* dst, int sd, int tid)
{
    const int kb = tid >> 3;
    const int cb = tid & 7;
    if (kb * 4 >= K) return;
    const int k0 = kb * 4;
    float e[4][4];
#pragma unroll
    for (int i = 0; i < 4; ++i) {
        const int o = ((k0 + i) * ldc + c0 + 4 * cb) >> 2;
        float4 w = ((const float4*)W)[o];
        int4   m = ((const int4*)M)[o];
        e[i][0] = m.x ? w.x : 0.f; e[i][1] = m.y ? w.y : 0.f;
        e[i][2] = m.z ? w.z : 0.f; e[i][3] = m.w ? w.w : 0.f;
    }
#pragma unroll
    for (int j = 0; j < 4; ++j) {
        ushort4 p;
        p.x = f16b(e[0][j]); p.y = f16b(e[1][j]);
        p.z = f16b(e[2][j]); p.w = f16b(e[3][j]);
        *(ushort4*)&dst[(4 * cb + j) * sd + k0] = p;
    }
}

// ReLU + fp16 pack of a C-frag (4 values), one 8B store at u16 offset o.
__device__ __forceinline__ void relu_store16(u16* __restrict__ dst, int o, f32x4_t a)
{
    ushort4 s;
    s.x = f16b(fmaxf(a[0], 0.f));
    s.y = f16b(fmaxf(a[1], 0.f));
    s.z = f16b(fmaxf(a[2], 0.f));
    s.w = f16b(fmaxf(a[3], 0.f));
    *(ushort4*)&dst[o] = s;
}

__global__ __launch_bounds__(512, 4)
void made_flow_r20(const float* __restrict__ inputs,
                   const float* __restrict__ W1,
                   const float* __restrict__ W2,
                   const float* __restrict__ Wout,
                   const int* __restrict__ idx,
                   const int* __restrict__ valid,
                   const int* __restrict__ M1,
                   const int* __restrict__ M2,
                   const int* __restrict__ Mout,
                   float* __restrict__ out)
{
    __shared__ __align__(16) u16 w1l[HH * SW1];        // 10240 B
    __shared__ __align__(16) u16 w2l[HH * SSC];        // 34816 B
    __shared__ __align__(16) u16 wol[OO * SSC];        // 17408 B
    __shared__ __align__(16) u16 stg[8][16 * SST];     // 10240 B
    // total 72704 B -> 2 blocks/CU

    const int tid  = threadIdx.x;
    const int r    = blockIdx.x >> 4;
    const int blk  = blockIdx.x & 15;
    const int lane = tid & 63;
    const int wave = tid >> 6;     // 0..7
    const int q    = lane >> 4;
    const int l16  = lane & 15;

    // ---- stage all weights -> shared LDS (single barrier) ----
    {
        const float* W1r = W1 + r * RR * HH;   const int* M1r = M1 + r * RR * HH;
        const float* W2r = W2 + r * HH * HH;   const int* M2r = M2 + r * HH * HH;
        const float* Wor = Wout + r * HH * OO; const int* Mor = Mout + r * HH * OO;
        // W1: 4 chunks of 32 cols (K=32), 128 threads each (64 active)
        {
            const int c  = tid >> 7;         // 0..3
            const int tp = tid & 127;
            stage_block16(W1r, M1r, HH, 32 * c, RR, w1l + 32 * c * SW1, SW1, tp);
        }
        // W2: 4 chunks of 32 cols (K=128), 2 rounds x 2 chunks (no barrier needed)
        for (int i = 0; i < 2; ++i) {
            if (tid < 256) stage_block16(W2r, M2r, HH, 32 * (2 * i),     HH,
                                         w2l + 32 * (2 * i) * SSC,     SSC, tid);
            else           stage_block16(W2r, M2r, HH, 32 * (2 * i + 1), HH,
                                         w2l + 32 * (2 * i + 1) * SSC, SSC, tid - 256);
        }
        // Wout: 2 chunks of 32 cols (K=128)
        if (tid < 256) stage_block16(Wor, Mor, OO, 0,  HH, wol,            SSC, tid);
        else           stage_block16(Wor, Mor, OO, 32, HH, wol + 32 * SSC, SSC, tid - 256);
    }
    __syncthreads();   // ONLY block barrier in the kernel

    u16* const mystg = stg[wave];
    const f32x4_t zero4 = {0.f, 0.f, 0.f, 0.f};

    // per-lane gather metadata: feats 8q..8q+7
    int   cidx[8];
    float cv[8];
#pragma unroll
    for (int j = 0; j < 8; ++j) {
        cidx[j] = idx[r * RR + 8 * q + j];
        cv[j]   = valid[r * RR + 8 * q + j] ? 1.f : 0.f;
    }
    const int row0 = blk * 512 + 64 * wave + l16;   // + 16*it

    // prefetch gather(0): lane (q,b=l16) loads feats 8q..8q+7 of row row0
    float g[8];
#pragma unroll
    for (int j = 0; j < 8; ++j) g[j] = inputs[row0 * DD + cidx[j]];

    for (int it = 0; it < 4; ++it) {
        const int row = row0 + 16 * it;

        // ---- xg B-frag directly from gathered regs ----
        union { u32 w[4]; f16x8_t v; } bx;
#pragma unroll
        for (int j2 = 0; j2 < 4; ++j2) {
            const float a0 = g[2 * j2]     * cv[2 * j2];
            const float a1 = g[2 * j2 + 1] * cv[2 * j2 + 1];
            bx.w[j2] = (u32)f16b(a0) | ((u32)f16b(a1) << 16);
        }

        // prefetch gather(it+1)
        if (it < 3) {
#pragma unroll
            for (int j = 0; j < 8; ++j) g[j] = inputs[(row + 16) * DD + cidx[j]];
        }

        // ---- epilogue x loads (f32, L2-hot), issued early ----
        float ex0[4], ex1[4], ev0[4], ev1[4];
#pragma unroll
        for (int mt3 = 0; mt3 < 4; ++mt3) {
            const int jb = r * RR + 8 * mt3 + 2 * q;
            int2 ii = *(const int2*)&idx[jb];
            int2 vv = *(const int2*)&valid[jb];
            ex0[mt3] = inputs[row * DD + ii.x];
            ex1[mt3] = inputs[row * DD + ii.y];
            ev0[mt3] = vv.x ? 1.f : 0.f;
            ev1[mt3] = vv.y ? 1.f : 0.f;
        }

        // ---- P1: h1 C-frags (8 M-tiles of 16 feats), A = W1^T from LDS ----
        f32x4_t c1[8];
#pragma unroll
        for (int mt = 0; mt < 8; ++mt) {
            f16x8_t af = *(const f16x8_t*)&w1l[(16 * mt + l16) * SW1 + 8 * q];
            c1[mt] = mfma16h(af, bx.v, zero4);
        }

        // ---- P2: stream h1 pairs through private stg; acc over 4 k-steps ----
        f32x4_t c2[8] = {zero4, zero4, zero4, zero4, zero4, zero4, zero4, zero4};
#pragma unroll
        for (int ksp = 0; ksp < 4; ++ksp) {
            relu_store16(mystg, l16 * SST + 4 * q,      c1[2 * ksp]);       // mt even
            relu_store16(mystg, l16 * SST + 16 + 4 * q, c1[2 * ksp + 1]);   // mt odd
            f16x8_t b1 = *(const f16x8_t*)&mystg[l16 * SST + 8 * q];
#pragma unroll
            for (int mt2 = 0; mt2 < 8; ++mt2) {
                f16x8_t wf = *(const f16x8_t*)&w2l[(16 * mt2 + l16) * SSC + 32 * ksp + 8 * q];
                c2[mt2] = mfma16h(wf, b1, c2[mt2]);
            }
        }

        // ---- P3: stream h2 pairs through private stg; acc over 4 k-steps ----
        f32x4_t c3[4] = {zero4, zero4, zero4, zero4};
#pragma unroll
        for (int ksp = 0; ksp < 4; ++ksp) {
            relu_store16(mystg, l16 * SST + 4 * q,      c2[2 * ksp]);
            relu_store16(mystg, l16 * SST + 16 + 4 * q, c2[2 * ksp + 1]);
            f16x8_t b2 = *(const f16x8_t*)&mystg[l16 * SST + 8 * q];
#pragma unroll
            for (int mt3 = 0; mt3 < 4; ++mt3) {
                f16x8_t wf = *(const f16x8_t*)&wol[(16 * mt3 + l16) * SSC + 32 * ksp + 8 * q];
                c3[mt3] = mfma16h(wf, b2, c3[mt3]);
            }
        }

        // ---- epilogue: c3[mt3][i]: i even=shift(j), i odd=log_s(j), j=8mt3+2q+(i>>1)
        float s = 0.f;
#pragma unroll
        for (int mt3 = 0; mt3 < 4; ++mt3) {
            const float u0 = (ex0[mt3] * ev0[mt3] - c3[mt3][0]) * __expf(-c3[mt3][1]);
            const float u1 = (ex1[mt3] * ev1[mt3] - c3[mt3][2]) * __expf(-c3[mt3][3]);
            s += (-0.5f * u0 * u0 - 0.91893853320467266954f - c3[mt3][1]) * ev0[mt3]
               + (-0.5f * u1 * u1 - 0.91893853320467266954f - c3[mt3][3]) * ev1[mt3];
        }
        s += __shfl_xor(s, 16, 64);
        s += __shfl_xor(s, 32, 64);
        if (q == 0) out[row * RR + r] = s;
    }
}

extern "C" void kernel_launch(void* const* d_in, const int* in_sizes, int n_in,
                              void* d_out, int out_size, void* d_ws, size_t ws_size,
                              hipStream_t stream)
{
    const float* inputs = (const float*)d_in[0];
    const float* W1     = (const float*)d_in[1];
    const float* W2     = (const float*)d_in[2];
    const float* Wout   = (const float*)d_in[3];
    const int*   idx    = (const int*)d_in[4];
    const int*   valid  = (const int*)d_in[5];
    const int*   M1     = (const int*)d_in[6];
    const int*   M2     = (const int*)d_in[7];
    const int*   Mout   = (const int*)d_in[8];
    float*       out    = (float*)d_out;

    hipLaunchKernelGGL(made_flow_r20, dim3(RR * 16), dim3(512), 0, stream,
                       inputs, W1, W2, Wout, idx, valid, M1, M2, Mout, out);
}

// Round 12
// 123.289 us; speedup vs baseline: 1.1309x; 1.1309x over previous
//
#include <hip/hip_runtime.h>
#include <math.h>

// AutoregressiveFlowLayer MI355X — round 21.
// R20 post-mortem (REGRESSION 64.5us, MfmaUtil 8.9, occ 30%): barrierless
// per-wave pipeline put the ds_write->ds_read->MFMA round-trip (~150cy, x8/iter)
// on a SERIAL critical path — 4 waves/SIMD of serial chains is worse than
// lockstep. Structural bets now 0-for-3 (R18/R20/R14). Champion: R19 47.2us.
// Surviving unexplained fact: identical structure, grid 768 (47.6) vs 1024
// (53) — with residency REG-PINNED at 2 blocks/CU, 768 = 3 blocks/CU of work
// leaves a lone-block tail phase (CU half-empty for ~p+10 tiles). Grid 512 =
// EXACTLY 2 blocks/CU was never tested: every CU runs 2 blocks concurrently
// start-to-finish, full 16 waves the whole dispatch, one preamble, no tail.
// R21 = R19 kernel with BLOCKS_PER_R 16, nt=16. NOTHING else changed (clean
// A/B on grid shape). LDS 41.3KB, (512,6), same phases/buffers.
// Predict: 47.2 -> 40-44us, occ 52-56, all other counters unchanged.
// If ~47: tail model wrong -> lockstep tau is the floor (structure ceiling).

#define RR 32
#define DD 1024
#define HH 128
#define OO 64
#define TROWS 32
#define TILES 16
#define BLOCKS_PER_R 16

#define SHP 136   // u16 stride, h planes [row][feat] (bank-balanced)
#define SXG 40    // u16 stride, xg plane [row][feat]
#define SSC 136   // u16 stride, weight staging / wout_lds [col][k]

typedef _Float16 f16x8_t __attribute__((ext_vector_type(8)));
typedef float f32x4_t __attribute__((ext_vector_type(4)));
typedef unsigned short u16;
typedef unsigned int u32;

__device__ __forceinline__ u16 f16b(float x) {
    _Float16 h = (_Float16)x;            // v_cvt_f16_f32, RNE
    union { _Float16 f; u16 u; } c; c.f = h; return c.u;
}
__device__ __forceinline__ f32x4_t mfma16h(f16x8_t a, f16x8_t b, f32x4_t c) {
    return __builtin_amdgcn_mfma_f32_16x16x32_f16(a, b, c, 0, 0, 0);
}

// stage [K x 32] weight slice (row-major [k][col], ld ldc, col offset c0) into
// fp16 [col][k] scratch (stride SSC), conflict-free 4x4 transpose. tid in [0,256).
__device__ __forceinline__ void stage_block16(const float* __restrict__ W,
                                              const int* __restrict__ M,
                                              int ldc, int c0, int K, u16* dst,
                                              int tid)
{
    const int kb = tid >> 3;
    const int cb = tid & 7;
    if (kb * 4 >= K) return;
    const int k0 = kb * 4;
    float e[4][4];
#pragma unroll
    for (int i = 0; i < 4; ++i) {
        const int o = ((k0 + i) * ldc + c0 + 4 * cb) >> 2;
        float4 w = ((const float4*)W)[o];
        int4   m = ((const int4*)M)[o];
        e[i][0] = m.x ? w.x : 0.f; e[i][1] = m.y ? w.y : 0.f;
        e[i][2] = m.z ? w.z : 0.f; e[i][3] = m.w ? w.w : 0.f;
    }
#pragma unroll
    for (int j = 0; j < 4; ++j) {
        ushort4 p;
        p.x = f16b(e[0][j]); p.y = f16b(e[1][j]);
        p.z = f16b(e[2][j]); p.w = f16b(e[3][j]);
        *(ushort4*)&dst[(4 * cb + j) * SSC + k0] = p;
    }
}

// ReLU + fp16 pack of 4 accumulator values, one 8B store.
__device__ __forceinline__ void relu_store16(u16* __restrict__ dst, int o, f32x4_t a)
{
    ushort4 s;
    s.x = f16b(fmaxf(a[0], 0.f));
    s.y = f16b(fmaxf(a[1], 0.f));
    s.z = f16b(fmaxf(a[2], 0.f));
    s.w = f16b(fmaxf(a[3], 0.f));
    *(ushort4*)&dst[o] = s;
}

__global__ __launch_bounds__(512, 6)
void made_flow_r21(const float* __restrict__ inputs,
                   const float* __restrict__ W1,
                   const float* __restrict__ W2,
                   const float* __restrict__ Wout,
                   const int* __restrict__ idx,
                   const int* __restrict__ valid,
                   const int* __restrict__ M1,
                   const int* __restrict__ M2,
                   const int* __restrict__ Mout,
                   float* __restrict__ out)
{
    __shared__ __align__(16) u16 h1s[TROWS * SHP];      // 8704 B (staging scratch A)
    __shared__ __align__(16) u16 h2s[TROWS * SHP];      // 8704 B (staging scratch B)
    __shared__ __align__(16) u16 wout_lds[OO * SSC];    // 17408 B (Wout^T resident)
    __shared__ __align__(16) u16 xgh[2][TROWS * SXG];   // 5120 B
    __shared__ __align__(16) float red2[2][TROWS][4];   // 1024 B
    __shared__ int   idx_s[RR];
    __shared__ float v_s[RR];
    // total ~41.3 KB

    u16* const scr  = h1s;
    u16* const scr2 = h2s;

    const int tid  = threadIdx.x;
    const int r    = blockIdx.x / BLOCKS_PER_R;
    const int rb   = blockIdx.x % BLOCKS_PER_R;
    const int ts   = rb * TILES;

    const int lane = tid & 63;
    const int wave = tid >> 6;     // 0..7
    const int q    = lane >> 4;
    const int l16  = lane & 15;
    const int wm3  = wave & 3;     // P3: o-col group 16*wm3
    const int ni3  = wave >> 2;    // P3: batch-row half

    if (tid < RR) {
        idx_s[tid] = idx[r * RR + tid];
        v_s[tid]   = valid[r * RR + tid] ? 1.f : 0.f;
    }

    // ---- stage weights: a1,a2 -> regs; Wout^T -> resident LDS ----
    f16x8_t a1;        // W1^T: wave cols 16w+l16, k=q*8..
    f16x8_t a2[4];     // W2^T: [ks], wave cols 16w+l16
    {
        const float* W1r = W1 + r * RR * HH;   const int* M1r = M1 + r * RR * HH;
        const float* W2r = W2 + r * HH * HH;   const int* M2r = M2 + r * HH * HH;
        const float* Wor = Wout + r * HH * OO; const int* Mor = Mout + r * HH * OO;
        const int c = wave >> 1, h = wave & 1;
        for (int i = 0; i < 2; ++i) {
            __syncthreads();
            if (tid < 256) stage_block16(W2r, M2r, HH, 32 * (2 * i),     HH, scr,  tid);
            else           stage_block16(W2r, M2r, HH, 32 * (2 * i + 1), HH, scr2, tid - 256);
            __syncthreads();
            if (c == 2 * i) {
#pragma unroll
                for (int ks = 0; ks < 4; ++ks)
                    a2[ks] = *(const f16x8_t*)&scr[(16 * h + l16) * SSC + ks * 32 + q * 8];
            } else if (c == 2 * i + 1) {
#pragma unroll
                for (int ks = 0; ks < 4; ++ks)
                    a2[ks] = *(const f16x8_t*)&scr2[(16 * h + l16) * SSC + ks * 32 + q * 8];
            }
        }
        for (int i = 0; i < 2; ++i) {
            __syncthreads();
            if (tid < 256) stage_block16(W1r, M1r, HH, 32 * (2 * i),     RR, scr,  tid);
            else           stage_block16(W1r, M1r, HH, 32 * (2 * i + 1), RR, scr2, tid - 256);
            __syncthreads();
            if (c == 2 * i)          a1 = *(const f16x8_t*)&scr [(16 * h + l16) * SSC + q * 8];
            else if (c == 2 * i + 1) a1 = *(const f16x8_t*)&scr2[(16 * h + l16) * SSC + q * 8];
        }
        // Wout^T -> wout_lds (read-only for the rest of the kernel)
        if (tid < 256) stage_block16(Wor, Mor, OO, 0,  HH, wout_lds,            tid);
        else           stage_block16(Wor, Mor, OO, 32, HH, wout_lds + 32 * SSC, tid - 256);
    }
    __syncthreads();   // staging done before xg/h1 writes; idx_s/v_s visible

    const f32x4_t zero4 = {0.f, 0.f, 0.f, 0.f};
    const int grow = tid >> 4;     // 0..31 batch row (gather role)
    const int gg   = tid & 15;     // col pair: 2*gg, 2*gg+1
    const int   ci0 = idx_s[2 * gg], ci1 = idx_s[2 * gg + 1];
    const float cv0 = v_s[2 * gg],   cv1 = v_s[2 * gg + 1];
    const int j0  = 8 * wm3 + 2 * q;                    // epilogue cols
    const float vj0 = v_s[j0], vj1 = v_s[j0 + 1];
    const int gbase = (ts * TROWS + grow) * DD;

    // ---- prologue: gather(0) -> xgh[0]; issue gather(1) into regs ----
    float gx0, gx1;
    {
        float a0  = inputs[gbase + ci0] * cv0;
        float a1v = inputs[gbase + ci1] * cv1;
        *(u32*)&xgh[0][grow * SXG + 2 * gg] = (u32)f16b(a0) | ((u32)f16b(a1v) << 16);
        gx0 = inputs[gbase + TROWS * DD + ci0] * cv0;
        gx1 = inputs[gbase + TROWS * DD + ci1] * cv1;
    }
    __syncthreads();

    // ---- prologue: P1(0) -> h1s ----
    {
#pragma unroll
        for (int ni = 0; ni < 2; ++ni) {
            f16x8_t b = *(const f16x8_t*)&xgh[0][(16 * ni + l16) * SXG + q * 8];
            f32x4_t a = mfma16h(a1, b, zero4);
            relu_store16(h1s, (16 * ni + l16) * SHP + 16 * wave + 4 * q, a);
        }
    }

    for (int t = 0; t < TILES; ++t) {
        __syncthreads();   // head barrier

        const bool dg = (t + 1 < TILES);

        // ========== interval A: gather-store(t+1) + P2(t) + out-store(t-2) ========
        if (dg) {
            *(u32*)&xgh[(t + 1) & 1][grow * SXG + 2 * gg] =
                (u32)f16b(gx0) | ((u32)f16b(gx1) << 16);
        }
        {
            // P2(t): h2^T = W2^T @ h1^T (wave owns 16 of M=128 cols, both ni, K=128)
            f32x4_t acc[2] = {zero4, zero4};
#pragma unroll
            for (int ks = 0; ks < 4; ++ks) {
#pragma unroll
                for (int ni = 0; ni < 2; ++ni) {
                    f16x8_t b = *(const f16x8_t*)&h1s[(16 * ni + l16) * SHP + ks * 32 + q * 8];
                    acc[ni] = mfma16h(a2[ks], b, acc[ni]);
                }
            }
#pragma unroll
            for (int ni = 0; ni < 2; ++ni)
                relu_store16(h2s, (16 * ni + l16) * SHP + 16 * wave + 4 * q, acc[ni]);
        }
        if (t >= 2 && tid < TROWS) {
            float4 rv = *(const float4*)&red2[t & 1][tid][0];
            out[((ts + (t - 2)) * TROWS + tid) * RR + r] =
                rv.x + rv.y + rv.z + rv.w;
        }
        __syncthreads();   // mid barrier

        // ========== interval B: gather-issue(t+2) + P3(t) + P1(t+1) + epilogue(t) ==
        if (t + 2 < TILES) {
            const int base = gbase + (t + 2) * (TROWS * DD);
            gx0 = inputs[base + ci0] * cv0;
            gx1 = inputs[base + ci1] * cv1;
        }

        // P3(t): out^T = Wout^T @ h2^T; wave (wm3,ni3): o=16*wm3+4q+i, row=16*ni3+l16
        // A-frags from resident wout_lds (4 bank-balanced ds_read_b128)
        f32x4_t acc3 = zero4;
#pragma unroll
        for (int ks = 0; ks < 4; ++ks) {
            f16x8_t ao = *(const f16x8_t*)&wout_lds[(16 * wm3 + l16) * SSC + ks * 32 + q * 8];
            f16x8_t b  = *(const f16x8_t*)&h2s[(16 * ni3 + l16) * SHP + ks * 32 + q * 8];
            acc3 = mfma16h(ao, b, acc3);
        }

        if (dg) {   // P1(t+1): h1^T = W1^T @ xg^T
#pragma unroll
            for (int ni = 0; ni < 2; ++ni) {
                f16x8_t b = *(const f16x8_t*)&xgh[(t + 1) & 1][(16 * ni + l16) * SXG + q * 8];
                f32x4_t a = mfma16h(a1, b, zero4);
                relu_store16(h1s, (16 * ni + l16) * SHP + 16 * wave + 4 * q, a);
            }
        }

        {   // epilogue(t): acc3[i]: i even=shift(j), i odd=log_s(j), j=8*wm3+2q+(i>>1)
            const int row = 16 * ni3 + l16;
            u32 xw = *(const u32*)&xgh[t & 1][row * SXG + j0];
            union { u32 u; _Float16 h[2]; } xc; xc.u = xw;
            const float xv0 = (float)xc.h[0], xv1 = (float)xc.h[1];
            const float u0 = (xv0 - acc3[0]) * __expf(-acc3[1]);
            const float u1 = (xv1 - acc3[2]) * __expf(-acc3[3]);
            float p = (-0.5f * u0 * u0 - 0.91893853320467266954f - acc3[1]) * vj0
                    + (-0.5f * u1 * u1 - 0.91893853320467266954f - acc3[3]) * vj1;
            p += __shfl_xor(p, 16, 64);
            p += __shfl_xor(p, 32, 64);
            if (q == 0) red2[t & 1][row][wm3] = p;
        }
    }

    // ---- tail: store tiles TILES-2 and TILES-1 ----
    __syncthreads();
    if (tid < 2 * TROWS) {
        const int tt  = TILES - 2 + (tid >> 5);
        const int row = tid & 31;
        float4 rv = *(const float4*)&red2[tt & 1][row][0];
        out[((ts + tt) * TROWS + row) * RR + r] =
            rv.x + rv.y + rv.z + rv.w;
    }
}

extern "C" void kernel_launch(void* const* d_in, const int* in_sizes, int n_in,
                              void* d_out, int out_size, void* d_ws, size_t ws_size,
                              hipStream_t stream)
{
    const float* inputs = (const float*)d_in[0];
    const float* W1     = (const float*)d_in[1];
    const float* W2     = (const float*)d_in[2];
    const float* Wout   = (const float*)d_in[3];
    const int*   idx    = (const int*)d_in[4];
    const int*   valid  = (const int*)d_in[5];
    const int*   M1     = (const int*)d_in[6];
    const int*   M2     = (const int*)d_in[7];
    const int*   Mout   = (const int*)d_in[8];
    float*       out    = (float*)d_out;

    hipLaunchKernelGGL(made_flow_r21, dim3(RR * BLOCKS_PER_R), dim3(512), 0, stream,
                       inputs, W1, W2, Wout, idx, valid, M1, M2, Mout, out);
}

// Round 14
// 121.135 us; speedup vs baseline: 1.1510x; 1.0178x over previous
//
#include <hip/hip_runtime.h>
#include <math.h>

// AutoregressiveFlowLayer MI355X — round 23 (= R22 with pkrtz type fix:
// __builtin_amdgcn_cvt_pkrtz returns __fp16 ext_vector(2), not _Float16).
// R21 post-mortem: grid 512 (exact 2 blocks/CU) = 48.6-50.8us, same band as
// R19's 47.2 -> tail model refuted. Ledger: 9 lockstep variants all 47-66us,
// every pipe <=26%. Consistency check: ~1750 cy/interval measured ~= serial
// SUM of per-SIMD pipe times (MFMA 320 + LDS ~600 + VALU ~700) + drain ->
// intra-interval chains too short for 4 waves/SIMD to overlap pipes.
// R22/23 attacks the work quantum (both untested):
//  (1) TROWS 32->64 (8 tiles/block, grid 512): HALVES barrier drains per output
//      row, DOUBLES independent chains per interval (P2: 4 acc chains). Same
//      total FLOPs. LDS 64.8KB -> still 2 blocks/CU.
//  (2) v_cvt_pkrtz_f16_f32 packing everywhere: pack path ~6 -> 2 VALU inst per
//      4 values (RTZ vs RNE irrelevant at 0.25 tol).
// Everything else = R21/R19 champion: fp16 single-plane, a1/a2 reg-frags, Wout
// resident LDS, 2-barrier schedule, T14 gather issue(t+2)/store(t+1),
// red2 + rolling out-store. __launch_bounds__(512,4) (cap 128, demand ~100).
// Predict: 47 -> 40-44us; VGPR<=80, WRITE ~1MB (spill check). If >=46us: the
// lockstep structure is at its latency ceiling -> declare.

#define RR 32
#define DD 1024
#define HH 128
#define OO 64
#define TROWS 64
#define TILES 8
#define BLOCKS_PER_R 16

#define SHP 136   // u16 stride, h planes [row][feat] (bank-balanced)
#define SXG 40    // u16 stride, xg plane [row][feat]
#define SSC 136   // u16 stride, weight staging / wout_lds [col][k]

typedef _Float16 f16x8_t __attribute__((ext_vector_type(8)));
typedef float f32x4_t __attribute__((ext_vector_type(4)));
typedef unsigned short u16;
typedef unsigned int u32;

__device__ __forceinline__ u32 pkrtz(float a, float b) {
    union { __fp16 v __attribute__((ext_vector_type(2))); u32 u; } c;
    c.v = __builtin_amdgcn_cvt_pkrtz(a, b);
    return c.u;
}
__device__ __forceinline__ f32x4_t mfma16h(f16x8_t a, f16x8_t b, f32x4_t c) {
    return __builtin_amdgcn_mfma_f32_16x16x32_f16(a, b, c, 0, 0, 0);
}

// stage [K x 32] weight slice (row-major [k][col], ld ldc, col offset c0) into
// fp16 [col][k] scratch (stride SSC), conflict-free 4x4 transpose. tid in [0,256).
__device__ __forceinline__ void stage_block16(const float* __restrict__ W,
                                              const int* __restrict__ M,
                                              int ldc, int c0, int K, u16* dst,
                                              int tid)
{
    const int kb = tid >> 3;
    const int cb = tid & 7;
    if (kb * 4 >= K) return;
    const int k0 = kb * 4;
    float e[4][4];
#pragma unroll
    for (int i = 0; i < 4; ++i) {
        const int o = ((k0 + i) * ldc + c0 + 4 * cb) >> 2;
        float4 w = ((const float4*)W)[o];
        int4   m = ((const int4*)M)[o];
        e[i][0] = m.x ? w.x : 0.f; e[i][1] = m.y ? w.y : 0.f;
        e[i][2] = m.z ? w.z : 0.f; e[i][3] = m.w ? w.w : 0.f;
    }
#pragma unroll
    for (int j = 0; j < 4; ++j) {
        uint2 p;
        p.x = pkrtz(e[0][j], e[1][j]);
        p.y = pkrtz(e[2][j], e[3][j]);
        *(uint2*)&dst[(4 * cb + j) * SSC + k0] = p;
    }
}

// ReLU + fp16 pack of 4 accumulator values, one 8B store.
__device__ __forceinline__ void relu_store16(u16* __restrict__ dst, int o, f32x4_t a)
{
    uint2 s;
    s.x = pkrtz(fmaxf(a[0], 0.f), fmaxf(a[1], 0.f));
    s.y = pkrtz(fmaxf(a[2], 0.f), fmaxf(a[3], 0.f));
    *(uint2*)&dst[o] = s;
}

__global__ __launch_bounds__(512, 4)
void made_flow_r23(const float* __restrict__ inputs,
                   const float* __restrict__ W1,
                   const float* __restrict__ W2,
                   const float* __restrict__ Wout,
                   const int* __restrict__ idx,
                   const int* __restrict__ valid,
                   const int* __restrict__ M1,
                   const int* __restrict__ M2,
                   const int* __restrict__ Mout,
                   float* __restrict__ out)
{
    __shared__ __align__(16) u16 h1s[TROWS * SHP];      // 17408 B (staging scratch A)
    __shared__ __align__(16) u16 h2s[TROWS * SHP];      // 17408 B (staging scratch B)
    __shared__ __align__(16) u16 wout_lds[OO * SSC];    // 17408 B (Wout^T resident)
    __shared__ __align__(16) u16 xgh[2][TROWS * SXG];   // 10240 B
    __shared__ __align__(16) float red2[2][TROWS][4];   // 2048 B
    __shared__ int   idx_s[RR];
    __shared__ float v_s[RR];
    // total ~64.8 KB -> 2 blocks/CU

    u16* const scr  = h1s;
    u16* const scr2 = h2s;

    const int tid  = threadIdx.x;
    const int r    = blockIdx.x / BLOCKS_PER_R;
    const int rb   = blockIdx.x % BLOCKS_PER_R;
    const int ts64 = rb * TILES * TROWS;     // first batch row of this block

    const int lane = tid & 63;
    const int wave = tid >> 6;     // 0..7
    const int q    = lane >> 4;
    const int l16  = lane & 15;
    const int wm3  = wave & 3;     // P3: o-col group 16*wm3
    const int ni3  = wave >> 2;    // P3: batch-row quarter base (ni3, ni3+2)

    if (tid < RR) {
        idx_s[tid] = idx[r * RR + tid];
        v_s[tid]   = valid[r * RR + tid] ? 1.f : 0.f;
    }

    // ---- stage weights: a1,a2 -> regs; Wout^T -> resident LDS ----
    f16x8_t a1;        // W1^T: wave cols 16w+l16, k=q*8..
    f16x8_t a2[4];     // W2^T: [ks], wave cols 16w+l16
    {
        const float* W1r = W1 + r * RR * HH;   const int* M1r = M1 + r * RR * HH;
        const float* W2r = W2 + r * HH * HH;   const int* M2r = M2 + r * HH * HH;
        const float* Wor = Wout + r * HH * OO; const int* Mor = Mout + r * HH * OO;
        const int c = wave >> 1, h = wave & 1;
        for (int i = 0; i < 2; ++i) {
            __syncthreads();
            if (tid < 256) stage_block16(W2r, M2r, HH, 32 * (2 * i),     HH, scr,  tid);
            else           stage_block16(W2r, M2r, HH, 32 * (2 * i + 1), HH, scr2, tid - 256);
            __syncthreads();
            if (c == 2 * i) {
#pragma unroll
                for (int ks = 0; ks < 4; ++ks)
                    a2[ks] = *(const f16x8_t*)&scr[(16 * h + l16) * SSC + ks * 32 + q * 8];
            } else if (c == 2 * i + 1) {
#pragma unroll
                for (int ks = 0; ks < 4; ++ks)
                    a2[ks] = *(const f16x8_t*)&scr2[(16 * h + l16) * SSC + ks * 32 + q * 8];
            }
        }
        for (int i = 0; i < 2; ++i) {
            __syncthreads();
            if (tid < 256) stage_block16(W1r, M1r, HH, 32 * (2 * i),     RR, scr,  tid);
            else           stage_block16(W1r, M1r, HH, 32 * (2 * i + 1), RR, scr2, tid - 256);
            __syncthreads();
            if (c == 2 * i)          a1 = *(const f16x8_t*)&scr [(16 * h + l16) * SSC + q * 8];
            else if (c == 2 * i + 1) a1 = *(const f16x8_t*)&scr2[(16 * h + l16) * SSC + q * 8];
        }
        // Wout^T -> wout_lds (read-only for the rest of the kernel)
        if (tid < 256) stage_block16(Wor, Mor, OO, 0,  HH, wout_lds,            tid);
        else           stage_block16(Wor, Mor, OO, 32, HH, wout_lds + 32 * SSC, tid - 256);
    }
    __syncthreads();   // staging done before xg/h1 writes; idx_s/v_s visible

    const f32x4_t zero4 = {0.f, 0.f, 0.f, 0.f};
    const int grow = tid >> 4;     // 0..31 (gather rows grow and grow+32)
    const int gg   = tid & 15;     // col pair: 2*gg, 2*gg+1
    const int   ci0 = idx_s[2 * gg], ci1 = idx_s[2 * gg + 1];
    const float cv0 = v_s[2 * gg],   cv1 = v_s[2 * gg + 1];
    const int j0  = 8 * wm3 + 2 * q;                    // epilogue cols
    const float vj0 = v_s[j0], vj1 = v_s[j0 + 1];
    const int gb0 = (ts64 + grow) * DD;
    const int gb1 = (ts64 + 32 + grow) * DD;

    // ---- prologue: gather(0) -> xgh[0]; issue gather(1) into regs ----
    float gx[4];
    {
        float a0 = inputs[gb0 + ci0] * cv0, a1v = inputs[gb0 + ci1] * cv1;
        float b0 = inputs[gb1 + ci0] * cv0, b1v = inputs[gb1 + ci1] * cv1;
        *(u32*)&xgh[0][grow * SXG + 2 * gg]        = pkrtz(a0, a1v);
        *(u32*)&xgh[0][(grow + 32) * SXG + 2 * gg] = pkrtz(b0, b1v);
        gx[0] = inputs[gb0 + TROWS * DD + ci0] * cv0;
        gx[1] = inputs[gb0 + TROWS * DD + ci1] * cv1;
        gx[2] = inputs[gb1 + TROWS * DD + ci0] * cv0;
        gx[3] = inputs[gb1 + TROWS * DD + ci1] * cv1;
    }
    __syncthreads();

    // ---- prologue: P1(0) -> h1s ----
    {
#pragma unroll
        for (int ni = 0; ni < 4; ++ni) {
            f16x8_t b = *(const f16x8_t*)&xgh[0][(16 * ni + l16) * SXG + q * 8];
            f32x4_t a = mfma16h(a1, b, zero4);
            relu_store16(h1s, (16 * ni + l16) * SHP + 16 * wave + 4 * q, a);
        }
    }

    for (int t = 0; t < TILES; ++t) {
        __syncthreads();   // head barrier

        const bool dg = (t + 1 < TILES);

        // ========== interval A: gather-store(t+1) + P2(t) + out-store(t-2) ========
        if (dg) {
            *(u32*)&xgh[(t + 1) & 1][grow * SXG + 2 * gg]        = pkrtz(gx[0], gx[1]);
            *(u32*)&xgh[(t + 1) & 1][(grow + 32) * SXG + 2 * gg] = pkrtz(gx[2], gx[3]);
        }
        {
            // P2(t): h2^T = W2^T @ h1^T (wave owns 16 of M=128 cols, 4 ni, K=128)
            f32x4_t acc[4] = {zero4, zero4, zero4, zero4};
#pragma unroll
            for (int ks = 0; ks < 4; ++ks) {
#pragma unroll
                for (int ni = 0; ni < 4; ++ni) {
                    f16x8_t b = *(const f16x8_t*)&h1s[(16 * ni + l16) * SHP + ks * 32 + q * 8];
                    acc[ni] = mfma16h(a2[ks], b, acc[ni]);
                }
            }
#pragma unroll
            for (int ni = 0; ni < 4; ++ni)
                relu_store16(h2s, (16 * ni + l16) * SHP + 16 * wave + 4 * q, acc[ni]);
        }
        if (t >= 2 && tid < TROWS) {
            float4 rv = *(const float4*)&red2[t & 1][tid][0];
            out[((rb * TILES + (t - 2)) * TROWS + tid) * RR + r] =
                rv.x + rv.y + rv.z + rv.w;
        }
        __syncthreads();   // mid barrier

        // ========== interval B: gather-issue(t+2) + P3(t) + P1(t+1) + epilogue(t) ==
        if (t + 2 < TILES) {
            const int base = (t + 2) * (TROWS * DD);
            gx[0] = inputs[gb0 + base + ci0] * cv0;
            gx[1] = inputs[gb0 + base + ci1] * cv1;
            gx[2] = inputs[gb1 + base + ci0] * cv0;
            gx[3] = inputs[gb1 + base + ci1] * cv1;
        }

        // P3(t): out^T = Wout^T @ h2^T; wave (wm3,ni3): o=16*wm3+4q+i,
        // rows 16*(ni3+2*nn)+l16, nn=0,1. A-frags from resident wout_lds.
        f32x4_t acc3[2] = {zero4, zero4};
#pragma unroll
        for (int ks = 0; ks < 4; ++ks) {
            f16x8_t ao = *(const f16x8_t*)&wout_lds[(16 * wm3 + l16) * SSC + ks * 32 + q * 8];
#pragma unroll
            for (int nn = 0; nn < 2; ++nn) {
                f16x8_t b = *(const f16x8_t*)&h2s[(16 * (ni3 + 2 * nn) + l16) * SHP + ks * 32 + q * 8];
                acc3[nn] = mfma16h(ao, b, acc3[nn]);
            }
        }

        if (dg) {   // P1(t+1): h1^T = W1^T @ xg^T
#pragma unroll
            for (int ni = 0; ni < 4; ++ni) {
                f16x8_t b = *(const f16x8_t*)&xgh[(t + 1) & 1][(16 * ni + l16) * SXG + q * 8];
                f32x4_t a = mfma16h(a1, b, zero4);
                relu_store16(h1s, (16 * ni + l16) * SHP + 16 * wave + 4 * q, a);
            }
        }

        // epilogue(t): acc3[nn][i]: i even=shift(j), i odd=log_s(j), j=8*wm3+2q+(i>>1)
#pragma unroll
        for (int nn = 0; nn < 2; ++nn) {
            const int row = 16 * (ni3 + 2 * nn) + l16;
            u32 xw = *(const u32*)&xgh[t & 1][row * SXG + j0];
            union { u32 u; _Float16 h[2]; } xc; xc.u = xw;
            const float xv0 = (float)xc.h[0], xv1 = (float)xc.h[1];
            f32x4_t a = acc3[nn];
            const float u0 = (xv0 - a[0]) * __expf(-a[1]);
            const float u1 = (xv1 - a[2]) * __expf(-a[3]);
            float p = (-0.5f * u0 * u0 - 0.91893853320467266954f - a[1]) * vj0
                    + (-0.5f * u1 * u1 - 0.91893853320467266954f - a[3]) * vj1;
            p += __shfl_xor(p, 16, 64);
            p += __shfl_xor(p, 32, 64);
            if (q == 0) red2[t & 1][row][wm3] = p;
        }
    }

    // ---- tail: store tiles TILES-2 and TILES-1 ----
    __syncthreads();
    if (tid < 2 * TROWS) {
        const int tt  = TILES - 2 + (tid >> 6);
        const int row = tid & 63;
        float4 rv = *(const float4*)&red2[tt & 1][row][0];
        out[((rb * TILES + tt) * TROWS + row) * RR + r] =
            rv.x + rv.y + rv.z + rv.w;
    }
}

extern "C" void kernel_launch(void* const* d_in, const int* in_sizes, int n_in,
                              void* d_out, int out_size, void* d_ws, size_t ws_size,
                              hipStream_t stream)
{
    const float* inputs = (const float*)d_in[0];
    const float* W1     = (const float*)d_in[1];
    const float* W2     = (const float*)d_in[2];
    const float* Wout   = (const float*)d_in[3];
    const int*   idx    = (const int*)d_in[4];
    const int*   valid  = (const int*)d_in[5];
    const int*   M1     = (const int*)d_in[6];
    const int*   M2     = (const int*)d_in[7];
    const int*   Mout   = (const int*)d_in[8];
    float*       out    = (float*)d_out;

    hipLaunchKernelGGL(made_flow_r23, dim3(RR * BLOCKS_PER_R), dim3(512), 0, stream,
                       inputs, W1, W2, Wout, idx, valid, M1, M2, Mout, out);
}

// Round 15
// 117.089 us; speedup vs baseline: 1.1907x; 1.0346x over previous
//
#include <hip/hip_runtime.h>
#include <math.h>

// AutoregressiveFlowLayer MI355X — round 24.
// R23 post-mortem (45.4us, best): TROWS=64 gave only +3-4%. NEW: absmax is a
// MEASUREMENT (0.25->0.5 with RTZ), tol >= 0.5. LDS re-audit: conflict cycles
// = 6.3M/256CU = 22% of dispatch ON TOP of ~35% read/store -> LDS ~55-60% busy,
// the leading pipe (dismissed in R11 without totaling). Geometry: row stride
// 272B -> lane-bank step 4 -> 64 lanes collapse onto one 8-bank coset (~8-way).
// Swizzle CAN'T fix (b128 16B granularity stays in the step-4 coset; odd-dword
// strides break alignment). But VOLUME can drop: P2 B-reads are 8x-duplicated.
// R24 = M4xN2 wave split for P1/P2, A stays register-resident:
//   wave = (mq=wave&3 -> cols 32mq..+32, nh=wave>>2 -> ni pair 2nh,2nh+1).
//   a2[2][4] (8 frags, +16 regs), a1[2]. P2: 16 MFMA (same), B-reads 16->8;
//   P1: 4 MFMA, reads 4->2. Block reads/tile 256->176 (-31%).
//   Regs ~95 < 128 cap at (512,4); LDS 64.8KB already pins 2 blocks/CU.
// + s_setprio(1) around P2/P3 MFMA clusters: 2 INDEPENDENT blocks/CU =
//   m191's cross-block arbitration regime (not m190's lockstep null).
// Predict: conflicts 6.3M->~4.2M; dur 45.4->39-43; no spill. If conflicts drop
// but dur >=45: LDS throughput wasn't critical path -> latency floor, declare.

#define RR 32
#define DD 1024
#define HH 128
#define OO 64
#define TROWS 64
#define TILES 8
#define BLOCKS_PER_R 16

#define SHP 136   // u16 stride, h planes [row][feat]
#define SXG 40    // u16 stride, xg plane [row][feat]
#define SSC 136   // u16 stride, weight staging / wout_lds [col][k]

typedef _Float16 f16x8_t __attribute__((ext_vector_type(8)));
typedef float f32x4_t __attribute__((ext_vector_type(4)));
typedef unsigned short u16;
typedef unsigned int u32;

__device__ __forceinline__ u32 pkrtz(float a, float b) {
    union { __fp16 v __attribute__((ext_vector_type(2))); u32 u; } c;
    c.v = __builtin_amdgcn_cvt_pkrtz(a, b);
    return c.u;
}
__device__ __forceinline__ f32x4_t mfma16h(f16x8_t a, f16x8_t b, f32x4_t c) {
    return __builtin_amdgcn_mfma_f32_16x16x32_f16(a, b, c, 0, 0, 0);
}

// stage [K x 32] weight slice (row-major [k][col], ld ldc, col offset c0) into
// fp16 [col][k] scratch (stride SSC), conflict-free 4x4 transpose. tid in [0,256).
__device__ __forceinline__ void stage_block16(const float* __restrict__ W,
                                              const int* __restrict__ M,
                                              int ldc, int c0, int K, u16* dst,
                                              int tid)
{
    const int kb = tid >> 3;
    const int cb = tid & 7;
    if (kb * 4 >= K) return;
    const int k0 = kb * 4;
    float e[4][4];
#pragma unroll
    for (int i = 0; i < 4; ++i) {
        const int o = ((k0 + i) * ldc + c0 + 4 * cb) >> 2;
        float4 w = ((const float4*)W)[o];
        int4   m = ((const int4*)M)[o];
        e[i][0] = m.x ? w.x : 0.f; e[i][1] = m.y ? w.y : 0.f;
        e[i][2] = m.z ? w.z : 0.f; e[i][3] = m.w ? w.w : 0.f;
    }
#pragma unroll
    for (int j = 0; j < 4; ++j) {
        uint2 p;
        p.x = pkrtz(e[0][j], e[1][j]);
        p.y = pkrtz(e[2][j], e[3][j]);
        *(uint2*)&dst[(4 * cb + j) * SSC + k0] = p;
    }
}

// ReLU + fp16 pack of 4 accumulator values, one 8B store.
__device__ __forceinline__ void relu_store16(u16* __restrict__ dst, int o, f32x4_t a)
{
    uint2 s;
    s.x = pkrtz(fmaxf(a[0], 0.f), fmaxf(a[1], 0.f));
    s.y = pkrtz(fmaxf(a[2], 0.f), fmaxf(a[3], 0.f));
    *(uint2*)&dst[o] = s;
}

__global__ __launch_bounds__(512, 4)
void made_flow_r24(const float* __restrict__ inputs,
                   const float* __restrict__ W1,
                   const float* __restrict__ W2,
                   const float* __restrict__ Wout,
                   const int* __restrict__ idx,
                   const int* __restrict__ valid,
                   const int* __restrict__ M1,
                   const int* __restrict__ M2,
                   const int* __restrict__ Mout,
                   float* __restrict__ out)
{
    __shared__ __align__(16) u16 h1s[TROWS * SHP];      // 17408 B (staging scratch A)
    __shared__ __align__(16) u16 h2s[TROWS * SHP];      // 17408 B (staging scratch B)
    __shared__ __align__(16) u16 wout_lds[OO * SSC];    // 17408 B (Wout^T resident)
    __shared__ __align__(16) u16 xgh[2][TROWS * SXG];   // 10240 B
    __shared__ __align__(16) float red2[2][TROWS][4];   // 2048 B
    __shared__ int   idx_s[RR];
    __shared__ float v_s[RR];
    // total ~64.8 KB -> 2 blocks/CU

    u16* const scr  = h1s;
    u16* const scr2 = h2s;

    const int tid  = threadIdx.x;
    const int r    = blockIdx.x / BLOCKS_PER_R;
    const int rb   = blockIdx.x % BLOCKS_PER_R;
    const int ts64 = rb * TILES * TROWS;     // first batch row of this block

    const int lane = tid & 63;
    const int wave = tid >> 6;     // 0..7
    const int q    = lane >> 4;
    const int l16  = lane & 15;
    const int mq   = wave & 3;     // P1/P2: col group 32*mq
    const int nh   = wave >> 2;    // P1/P2: ni pair {2nh, 2nh+1}
    const int wm3  = wave & 3;     // P3: o-col group 16*wm3
    const int ni3  = wave >> 2;    // P3: batch-row quarter base (ni3, ni3+2)

    if (tid < RR) {
        idx_s[tid] = idx[r * RR + tid];
        v_s[tid]   = valid[r * RR + tid] ? 1.f : 0.f;
    }

    // ---- stage weights: a1[2], a2[2][4] -> regs; Wout^T -> resident LDS ----
    f16x8_t a1[2];      // W1^T: cols 32mq+16mi+l16, k=q*8..
    f16x8_t a2[2][4];   // W2^T: [mi][ks], cols 32mq+16mi+l16
    {
        const float* W1r = W1 + r * RR * HH;   const int* M1r = M1 + r * RR * HH;
        const float* W2r = W2 + r * HH * HH;   const int* M2r = M2 + r * HH * HH;
        const float* Wor = Wout + r * HH * OO; const int* Mor = Mout + r * HH * OO;
        for (int i = 0; i < 2; ++i) {
            __syncthreads();
            if (tid < 256) stage_block16(W2r, M2r, HH, 32 * (2 * i),     HH, scr,  tid);
            else           stage_block16(W2r, M2r, HH, 32 * (2 * i + 1), HH, scr2, tid - 256);
            __syncthreads();
            if (mq == 2 * i) {
#pragma unroll
                for (int mi = 0; mi < 2; ++mi)
#pragma unroll
                    for (int ks = 0; ks < 4; ++ks)
                        a2[mi][ks] = *(const f16x8_t*)&scr[(16 * mi + l16) * SSC + ks * 32 + q * 8];
            } else if (mq == 2 * i + 1) {
#pragma unroll
                for (int mi = 0; mi < 2; ++mi)
#pragma unroll
                    for (int ks = 0; ks < 4; ++ks)
                        a2[mi][ks] = *(const f16x8_t*)&scr2[(16 * mi + l16) * SSC + ks * 32 + q * 8];
            }
        }
        for (int i = 0; i < 2; ++i) {
            __syncthreads();
            if (tid < 256) stage_block16(W1r, M1r, HH, 32 * (2 * i),     RR, scr,  tid);
            else           stage_block16(W1r, M1r, HH, 32 * (2 * i + 1), RR, scr2, tid - 256);
            __syncthreads();
            if (mq == 2 * i) {
#pragma unroll
                for (int mi = 0; mi < 2; ++mi)
                    a1[mi] = *(const f16x8_t*)&scr [(16 * mi + l16) * SSC + q * 8];
            } else if (mq == 2 * i + 1) {
#pragma unroll
                for (int mi = 0; mi < 2; ++mi)
                    a1[mi] = *(const f16x8_t*)&scr2[(16 * mi + l16) * SSC + q * 8];
            }
        }
        // Wout^T -> wout_lds (read-only for the rest of the kernel)
        if (tid < 256) stage_block16(Wor, Mor, OO, 0,  HH, wout_lds,            tid);
        else           stage_block16(Wor, Mor, OO, 32, HH, wout_lds + 32 * SSC, tid - 256);
    }
    __syncthreads();   // staging done before xg/h1 writes; idx_s/v_s visible

    const f32x4_t zero4 = {0.f, 0.f, 0.f, 0.f};
    const int grow = tid >> 4;     // 0..31 (gather rows grow and grow+32)
    const int gg   = tid & 15;     // col pair: 2*gg, 2*gg+1
    const int   ci0 = idx_s[2 * gg], ci1 = idx_s[2 * gg + 1];
    const float cv0 = v_s[2 * gg],   cv1 = v_s[2 * gg + 1];
    const int j0  = 8 * wm3 + 2 * q;                    // epilogue cols
    const float vj0 = v_s[j0], vj1 = v_s[j0 + 1];
    const int gb0 = (ts64 + grow) * DD;
    const int gb1 = (ts64 + 32 + grow) * DD;

    // ---- prologue: gather(0) -> xgh[0]; issue gather(1) into regs ----
    float gx[4];
    {
        float a0 = inputs[gb0 + ci0] * cv0, a1v = inputs[gb0 + ci1] * cv1;
        float b0 = inputs[gb1 + ci0] * cv0, b1v = inputs[gb1 + ci1] * cv1;
        *(u32*)&xgh[0][grow * SXG + 2 * gg]        = pkrtz(a0, a1v);
        *(u32*)&xgh[0][(grow + 32) * SXG + 2 * gg] = pkrtz(b0, b1v);
        gx[0] = inputs[gb0 + TROWS * DD + ci0] * cv0;
        gx[1] = inputs[gb0 + TROWS * DD + ci1] * cv1;
        gx[2] = inputs[gb1 + TROWS * DD + ci0] * cv0;
        gx[3] = inputs[gb1 + TROWS * DD + ci1] * cv1;
    }
    __syncthreads();

    // ---- prologue: P1(0) -> h1s (M4xN2 split) ----
    {
#pragma unroll
        for (int nn = 0; nn < 2; ++nn) {
            const int rw = 16 * (2 * nh + nn) + l16;
            f16x8_t b = *(const f16x8_t*)&xgh[0][rw * SXG + q * 8];
#pragma unroll
            for (int mi = 0; mi < 2; ++mi) {
                f32x4_t a = mfma16h(a1[mi], b, zero4);
                relu_store16(h1s, rw * SHP + 32 * mq + 16 * mi + 4 * q, a);
            }
        }
    }

    for (int t = 0; t < TILES; ++t) {
        __syncthreads();   // head barrier

        const bool dg = (t + 1 < TILES);

        // ========== interval A: gather-store(t+1) + P2(t) + out-store(t-2) ========
        if (dg) {
            *(u32*)&xgh[(t + 1) & 1][grow * SXG + 2 * gg]        = pkrtz(gx[0], gx[1]);
            *(u32*)&xgh[(t + 1) & 1][(grow + 32) * SXG + 2 * gg] = pkrtz(gx[2], gx[3]);
        }
        {
            // P2(t): wave owns cols 32mq..+32, rows ni=2nh,2nh+1; 16 MFMA, 8 B-reads
            f32x4_t acc[2][2] = {{zero4, zero4}, {zero4, zero4}};
            __builtin_amdgcn_s_setprio(1);
#pragma unroll
            for (int ks = 0; ks < 4; ++ks) {
#pragma unroll
                for (int nn = 0; nn < 2; ++nn) {
                    f16x8_t b = *(const f16x8_t*)&h1s[(16 * (2 * nh + nn) + l16) * SHP + ks * 32 + q * 8];
#pragma unroll
                    for (int mi = 0; mi < 2; ++mi)
                        acc[mi][nn] = mfma16h(a2[mi][ks], b, acc[mi][nn]);
                }
            }
            __builtin_amdgcn_s_setprio(0);
#pragma unroll
            for (int mi = 0; mi < 2; ++mi)
#pragma unroll
                for (int nn = 0; nn < 2; ++nn)
                    relu_store16(h2s, (16 * (2 * nh + nn) + l16) * SHP + 32 * mq + 16 * mi + 4 * q,
                                 acc[mi][nn]);
        }
        if (t >= 2 && tid < TROWS) {
            float4 rv = *(const float4*)&red2[t & 1][tid][0];
            out[((rb * TILES + (t - 2)) * TROWS + tid) * RR + r] =
                rv.x + rv.y + rv.z + rv.w;
        }
        __syncthreads();   // mid barrier

        // ========== interval B: gather-issue(t+2) + P3(t) + P1(t+1) + epilogue(t) ==
        if (t + 2 < TILES) {
            const int base = (t + 2) * (TROWS * DD);
            gx[0] = inputs[gb0 + base + ci0] * cv0;
            gx[1] = inputs[gb0 + base + ci1] * cv1;
            gx[2] = inputs[gb1 + base + ci0] * cv0;
            gx[3] = inputs[gb1 + base + ci1] * cv1;
        }

        // P3(t): out^T = Wout^T @ h2^T; wave (wm3,ni3): o=16*wm3+4q+i,
        // rows 16*(ni3+2*nn)+l16, nn=0,1. A-frags from resident wout_lds.
        f32x4_t acc3[2] = {zero4, zero4};
        __builtin_amdgcn_s_setprio(1);
#pragma unroll
        for (int ks = 0; ks < 4; ++ks) {
            f16x8_t ao = *(const f16x8_t*)&wout_lds[(16 * wm3 + l16) * SSC + ks * 32 + q * 8];
#pragma unroll
            for (int nn = 0; nn < 2; ++nn) {
                f16x8_t b = *(const f16x8_t*)&h2s[(16 * (ni3 + 2 * nn) + l16) * SHP + ks * 32 + q * 8];
                acc3[nn] = mfma16h(ao, b, acc3[nn]);
            }
        }
        __builtin_amdgcn_s_setprio(0);

        if (dg) {   // P1(t+1): M4xN2 split
#pragma unroll
            for (int nn = 0; nn < 2; ++nn) {
                const int rw = 16 * (2 * nh + nn) + l16;
                f16x8_t b = *(const f16x8_t*)&xgh[(t + 1) & 1][rw * SXG + q * 8];
#pragma unroll
                for (int mi = 0; mi < 2; ++mi) {
                    f32x4_t a = mfma16h(a1[mi], b, zero4);
                    relu_store16(h1s, rw * SHP + 32 * mq + 16 * mi + 4 * q, a);
                }
            }
        }

        // epilogue(t): acc3[nn][i]: i even=shift(j), i odd=log_s(j), j=8*wm3+2q+(i>>1)
#pragma unroll
        for (int nn = 0; nn < 2; ++nn) {
            const int row = 16 * (ni3 + 2 * nn) + l16;
            u32 xw = *(const u32*)&xgh[t & 1][row * SXG + j0];
            union { u32 u; _Float16 h[2]; } xc; xc.u = xw;
            const float xv0 = (float)xc.h[0], xv1 = (float)xc.h[1];
            f32x4_t a = acc3[nn];
            const float u0 = (xv0 - a[0]) * __expf(-a[1]);
            const float u1 = (xv1 - a[2]) * __expf(-a[3]);
            float p = (-0.5f * u0 * u0 - 0.91893853320467266954f - a[1]) * vj0
                    + (-0.5f * u1 * u1 - 0.91893853320467266954f - a[3]) * vj1;
            p += __shfl_xor(p, 16, 64);
            p += __shfl_xor(p, 32, 64);
            if (q == 0) red2[t & 1][row][wm3] = p;
        }
    }

    // ---- tail: store tiles TILES-2 and TILES-1 ----
    __syncthreads();
    if (tid < 2 * TROWS) {
        const int tt  = TILES - 2 + (tid >> 6);
        const int row = tid & 63;
        float4 rv = *(const float4*)&red2[tt & 1][row][0];
        out[((rb * TILES + tt) * TROWS + row) * RR + r] =
            rv.x + rv.y + rv.z + rv.w;
    }
}

extern "C" void kernel_launch(void* const* d_in, const int* in_sizes, int n_in,
                              void* d_out, int out_size, void* d_ws, size_t ws_size,
                              hipStream_t stream)
{
    const float* inputs = (const float*)d_in[0];
    const float* W1     = (const float*)d_in[1];
    const float* W2     = (const float*)d_in[2];
    const float* Wout   = (const float*)d_in[3];
    const int*   idx    = (const int*)d_in[4];
    const int*   valid  = (const int*)d_in[5];
    const int*   M1     = (const int*)d_in[6];
    const int*   M2     = (const int*)d_in[7];
    const int*   Mout   = (const int*)d_in[8];
    float*       out    = (float*)d_out;

    hipLaunchKernelGGL(made_flow_r24, dim3(RR * BLOCKS_PER_R), dim3(512), 0, stream,
                       inputs, W1, W2, Wout, idx, valid, M1, M2, Mout, out);
}